// Round 2
// baseline (288.392 us; speedup 1.0000x reference)
//
#include <hip/hip_runtime.h>
#include <math.h>

#define N_TOK 40
#define N1    41      // N_TOK + 1
#define BS    8
#define DD    256     // D
#define HH    256     // H
#define NTRI  10660   // C(41,3)
#define NPAIR 780     // pairs (i,k) with k-i>=2
#define NPTASK (NPAIR * BS)   // 6240 tasks, 16 lanes each
#define ROWF  (BS * N1 * HH)  // 83968 floats per [b][t][h] array
#define MNEG  (-1e38f)
#define DPB   256     // DP block: 4 waves
#define NB    390     // fused grid: NPTASK*16/256 exactly

// Monotonic grid barrier counter. Module-scope .bss: zero at load, NEVER
// reset (epoch is derived from each block's own ticket), so it is immune
// to workspace poisoning and works across graph replays.
__device__ unsigned long long g_bar;

// All 390 blocks call this at each barrier point. wait=false: arrive only.
__device__ __forceinline__ void grid_arrive(bool wait)
{
    __syncthreads();                       // block's writes done
    if (threadIdx.x == 0) {
        __threadfence();                   // agent-scope release of data
        unsigned long long t = __hip_atomic_fetch_add(
            &g_bar, 1ull, __ATOMIC_ACQ_REL, __HIP_MEMORY_SCOPE_AGENT);
        if (wait) {
            unsigned long long target = (t / NB + 1ull) * (unsigned long long)NB;
            while (__hip_atomic_load(&g_bar, __ATOMIC_ACQUIRE,
                                     __HIP_MEMORY_SCOPE_AGENT) < target)
                __builtin_amdgcn_s_sleep(2);
        }
    }
    __syncthreads();                       // release whole block
}

// ---------------- DP helpers (identical to previous k_dp) ----------------
__device__ __forceinline__ int tri_base(int i) { return (i * (81 - i)) >> 1; }
#define BIDX(i, j) (tri_base(i) + ((j) - (i) - 1))

constexpr int soff(int W) {
    int s = 0;
    for (int v = 2; v < W; ++v) s += (N1 - v) * (v - 1);
    return s;
}
constexpr int pick_T(int m, int nj) {
    int T = 1;
    while (T < 16 && m * (T * 2) <= DPB && T < nj) T *= 2;
    return T;
}

template<int W>
__device__ __forceinline__ void dp_step(float* __restrict__ Btri,
                                        const float* __restrict__ Sl, int tid)
{
    constexpr int m    = N1 - W;
    constexpr int nj   = W - 1;
    constexpr int T    = pick_T(m, nj);
    constexpr int CH   = (nj + T - 1) / T;
    constexpr int base = soff(W);

    if (tid < m * T) {
        const int i = tid / T;
        const int h = tid % T;
        const int k = i + W;

        float g[CH];
        #pragma unroll
        for (int q = 0; q < CH; ++q) {
            int jp = h + q * T;
            bool live = (q < CH - 1) || (jp < nj);
            int jj = live ? jp : 0;
            float v = Sl[base + i * nj + jj]
                    + Btri[BIDX(i, i + 1 + jj)]
                    + Btri[BIDX(i + 1 + jj, k)];
            g[q] = live ? v : MNEG;
        }
        float mx = g[0];
        #pragma unroll
        for (int q = 1; q < CH; ++q) mx = fmaxf(mx, g[q]);
        float s = 0.f;
        #pragma unroll
        for (int q = 0; q < CH; ++q) s += __expf(g[q] - mx);
        #pragma unroll
        for (int d = 1; d < T; d <<= 1) {
            float mo = __shfl_xor(mx, d);
            float so = __shfl_xor(s, d);
            float nm = fmaxf(mx, mo);
            s = s * __expf(mx - nm) + so * __expf(mo - nm);
            mx = nm;
        }
        if (h == 0)
            Btri[BIDX(i, k)] = mx + __logf(s);
    }
    __syncthreads();
}

template<int W>
__device__ __forceinline__ void dp_from(float* __restrict__ Btri,
                                        const float* __restrict__ Sl, int tid)
{
    dp_step<W>(Btri, Sl, tid);
    if constexpr (W + 1 <= N_TOK) dp_from<W + 1>(Btri, Sl, tid);
}

// ---------------- Fused kernel: proj -> [grid bar] -> score -> [grid bar] -> dp
__global__ __launch_bounds__(256) void k_fused(
    const float* __restrict__ enc, const float* __restrict__ W1,
    const float* __restrict__ b1,  const float* __restrict__ W2,
    const float* __restrict__ b2,  const int* __restrict__ lengths,
    float* __restrict__ P, float* __restrict__ Qb, float* __restrict__ Dd,
    float* __restrict__ S, float* __restrict__ out)
{
    const int tid = threadIdx.x;
    const int blk = blockIdx.x;

    __shared__ __align__(16) union SH {
        float e[BS][DD];                                  // proj: 8 KB
        struct { float Sl[NTRI]; float Btri[820]; } dp;   // dp: 45920 B
    } sh;

    // ======== phase 1: projections (blocks 0..40, body verbatim k_proj)
    if (blk < N1) {
        const int t = blk;
        const int h = tid;
        #pragma unroll
        for (int b = 0; b < BS; ++b)
            sh.e[b][h] = enc[(t * BS + b) * DD + h];
        __syncthreads();

        float accP[BS], accQ[BS];
        #pragma unroll
        for (int b = 0; b < BS; ++b) { accP[b] = 0.f; accQ[b] = 0.f; }

        for (int d = 0; d < DD; ++d) {
            float wp = W1[d * HH + h];
            float wq = W1[(DD + d) * HH + h];
            #pragma unroll
            for (int b = 0; b < BS; ++b) {
                float ev = sh.e[b][d];
                accP[b] = fmaf(ev, wp, accP[b]);
                accQ[b] = fmaf(ev, wq, accQ[b]);
            }
        }
        float bb = b1[h];
        #pragma unroll
        for (int b = 0; b < BS; ++b) {
            int idx = ((b * N1) + t) * HH + h;
            P[idx]  = accP[b];
            Qb[idx] = accQ[b] + bb;
            Dd[idx] = accP[b] - accQ[b];
        }
    }
    grid_arrive(true);    // P/Qb/Dd visible to all blocks

    // ======== phase 2: scores (all 390 blocks, body verbatim k_score)
    {
        const int gt   = blk * 256 + tid;
        const int task = gt >> 4;        // (pair, b), b fastest
        const int t    = gt & 15;

        const int p = task >> 3;         // pair index, w descending
        const int b = task & 7;

        int c = (int)((sqrtf(8.f * (float)p + 1.f) - 1.f) * 0.5f);
        while ((c + 1) * (c + 2) / 2 <= p) ++c;
        while (c * (c + 1) / 2 > p) --c;
        const int w    = 40 - c;
        const int i    = p - c * (c + 1) / 2;
        const int k    = i + w;
        const int nj   = w - 1;
        const int n2   = w - 2;
        const int base = n2 * (n2 + 1) * (119 - 2 * n2) / 6;   // == soff(w)

        const float4* Pr  = (const float4*)(P  + ((b * N1 + i) << 8)) + t * 4;
        const float4* Qr  = (const float4*)(Qb + ((b * N1 + k) << 8)) + t * 4;
        const float4* W2r = (const float4*)(W2) + t * 8;

        float4 pp[4], qq[4], wa[4], wb[4];
        #pragma unroll
        for (int q = 0; q < 4; ++q) {
            pp[q] = Pr[q]; qq[q] = Qr[q];
            wa[q] = W2r[q * 2]; wb[q] = W2r[q * 2 + 1];
        }
        const float bb0 = b2[0], bb1 = b2[1];

        const float4* Drow = (const float4*)(Dd + ((b * N1 + i + 1) << 8)) + t * 4;
        float* Sout = S + b * NTRI + base + i * nj;

        for (int jp = 0; jp < nj; ++jp) {
            float s0 = 0.f, s1 = 0.f;
            #pragma unroll
            for (int q = 0; q < 4; ++q) {
                float4 dd = Drow[q];
                float r0 = fmaxf(dd.x + qq[q].x - pp[q].x, 0.f);
                float r1 = fmaxf(dd.y + qq[q].y - pp[q].y, 0.f);
                float r2 = fmaxf(dd.z + qq[q].z - pp[q].z, 0.f);
                float r3 = fmaxf(dd.w + qq[q].w - pp[q].w, 0.f);
                s0 = fmaf(r0, wa[q].x, s0); s1 = fmaf(r0, wa[q].y, s1);
                s0 = fmaf(r1, wa[q].z, s0); s1 = fmaf(r1, wa[q].w, s1);
                s0 = fmaf(r2, wb[q].x, s0); s1 = fmaf(r2, wb[q].y, s1);
                s0 = fmaf(r3, wb[q].z, s0); s1 = fmaf(r3, wb[q].w, s1);
            }
            #pragma unroll
            for (int d = 1; d < 16; d <<= 1) {
                s0 += __shfl_xor(s0, d);
                s1 += __shfl_xor(s1, d);
            }
            if (t == 0) {
                float S0 = s0 + bb0, S1 = s1 + bb1;
                Sout[jp] = fmaxf(S0, S1) + log1pf(__expf(-fabsf(S0 - S1)));
            }
            Drow += 64;
        }
    }

    // ======== barrier 2: blocks >= 8 arrive and exit; blocks 0..7 wait
    if (blk >= BS) { grid_arrive(false); return; }
    grid_arrive(true);    // all S visible to DP blocks

    // ======== phase 3: DP (blocks 0..7, body verbatim k_dp)
    {
        const int b = blk;
        const float4* src = (const float4*)(S + b * NTRI);
        float4* dst = (float4*)sh.dp.Sl;
        for (int x = tid; x < NTRI / 4; x += DPB) dst[x] = src[x];
        if (tid < N_TOK) sh.dp.Btri[tri_base(tid)] = 0.f;
        __syncthreads();

        dp_from<2>(sh.dp.Btri, sh.dp.Sl, tid);

        if (tid == 0) {
            int L = lengths[b];
            out[b] = sh.dp.Btri[BIDX(0, L)];
        }
    }
}

extern "C" void kernel_launch(void* const* d_in, const int* in_sizes, int n_in,
                              void* d_out, int out_size, void* d_ws, size_t ws_size,
                              hipStream_t stream)
{
    const float* enc = (const float*)d_in[0];
    const float* W1  = (const float*)d_in[1];
    const float* b1  = (const float*)d_in[2];
    const float* W2  = (const float*)d_in[3];
    const float* b2  = (const float*)d_in[4];
    const int* lengths = (const int*)d_in[5];

    float* ws = (float*)d_ws;
    float* P  = ws;
    float* Qb = ws + ROWF;
    float* Dd = ws + 2 * ROWF;
    float* S  = ws + 3 * ROWF;   // NTRI*BS floats; total ws use ~1.35 MB

    k_fused<<<dim3(NB), dim3(256), 0, stream>>>(
        enc, W1, b1, W2, b2, lengths, P, Qb, Dd, S, (float*)d_out);
}

// Round 3
// 157.674 us; speedup vs baseline: 1.8290x; 1.8290x over previous
//
#include <hip/hip_runtime.h>
#include <math.h>

#define N_TOK 40
#define N1    41      // N_TOK + 1
#define BS    8
#define DD    256     // D
#define HH    256     // H
#define NTRI  10660   // C(41,3)
#define NPAIR 780     // pairs (i,k) with k-i>=2
#define ROWF  (BS * N1 * HH)  // 83968 floats per [b][t][h] array
#define MNEG  (-1e38f)
#define DPB   256
#define GPB   49      // blocks per batch group: 780 pairs * 16 lanes / 256 = 48.75
#define NBF   (BS * GPB)   // 392 blocks

// ---- persistent sync state (module .bss: zero at load) ----
// g_proj / g_sctr are reset to 0 at the END of each launch by the last DP
// block (epoch via monotonic g_fin % 8), so every launch starts from zero.
// Kernel-end implicit flush + sequential stream ordering make resets visible.
__device__ unsigned long long g_proj;          // proj arrivals (41 per launch)
__device__ unsigned long long g_sctr[BS * 16]; // per-b score arrivals, 128B stride
__device__ unsigned long long g_fin;           // monotonic, never reset

// ---------------- DP helpers (verbatim) ----------------
__device__ __forceinline__ int tri_base(int i) { return (i * (81 - i)) >> 1; }
#define BIDX(i, j) (tri_base(i) + ((j) - (i) - 1))

constexpr int soff(int W) {
    int s = 0;
    for (int v = 2; v < W; ++v) s += (N1 - v) * (v - 1);
    return s;
}
constexpr int pick_T(int m, int nj) {
    int T = 1;
    while (T < 16 && m * (T * 2) <= DPB && T < nj) T *= 2;
    return T;
}

template<int W>
__device__ __forceinline__ void dp_step(float* __restrict__ Btri,
                                        const float* __restrict__ Sl, int tid)
{
    constexpr int m    = N1 - W;
    constexpr int nj   = W - 1;
    constexpr int T    = pick_T(m, nj);
    constexpr int CH   = (nj + T - 1) / T;
    constexpr int base = soff(W);

    if (tid < m * T) {
        const int i = tid / T;
        const int h = tid % T;
        const int k = i + W;

        float g[CH];
        #pragma unroll
        for (int q = 0; q < CH; ++q) {
            int jp = h + q * T;
            bool live = (q < CH - 1) || (jp < nj);
            int jj = live ? jp : 0;
            float v = Sl[base + i * nj + jj]
                    + Btri[BIDX(i, i + 1 + jj)]
                    + Btri[BIDX(i + 1 + jj, k)];
            g[q] = live ? v : MNEG;
        }
        float mx = g[0];
        #pragma unroll
        for (int q = 1; q < CH; ++q) mx = fmaxf(mx, g[q]);
        float s = 0.f;
        #pragma unroll
        for (int q = 0; q < CH; ++q) s += __expf(g[q] - mx);
        #pragma unroll
        for (int d = 1; d < T; d <<= 1) {
            float mo = __shfl_xor(mx, d);
            float so = __shfl_xor(s, d);
            float nm = fmaxf(mx, mo);
            s = s * __expf(mx - nm) + so * __expf(mo - nm);
            mx = nm;
        }
        if (h == 0)
            Btri[BIDX(i, k)] = mx + __logf(s);
    }
    __syncthreads();
}

template<int W>
__device__ __forceinline__ void dp_from(float* __restrict__ Btri,
                                        const float* __restrict__ Sl, int tid)
{
    dp_step<W>(Btri, Sl, tid);
    if constexpr (W + 1 <= N_TOK) dp_from<W + 1>(Btri, Sl, tid);
}

// ---------------- Fused: proj -> [flag] -> score(per-b groups) -> [per-b ctr] -> dp
__global__ __launch_bounds__(256) void k_fused(
    const float* __restrict__ enc, const float* __restrict__ W1,
    const float* __restrict__ b1,  const float* __restrict__ W2,
    const float* __restrict__ b2,  const int* __restrict__ lengths,
    float* __restrict__ P, float* __restrict__ Qb, float* __restrict__ Dd,
    float* __restrict__ S, float* __restrict__ out)
{
    const int tid = threadIdx.x;
    const int blk = blockIdx.x;
    const int b   = blk / GPB;        // batch group
    const int g   = blk - b * GPB;    // block index within group

    __shared__ __align__(16) union SH {
        float e[BS][DD];                                  // proj: 8 KB
        struct { float Sl[NTRI]; float Btri[820]; } dp;   // dp: 45920 B
    } sh;

    // ======== phase 1: projections (blocks 0..40 == group-0 blocks, verbatim)
    if (blk < N1) {
        const int t = blk;
        const int h = tid;
        #pragma unroll
        for (int bb_ = 0; bb_ < BS; ++bb_)
            sh.e[bb_][h] = enc[(t * BS + bb_) * DD + h];
        __syncthreads();

        float accP[BS], accQ[BS];
        #pragma unroll
        for (int bb_ = 0; bb_ < BS; ++bb_) { accP[bb_] = 0.f; accQ[bb_] = 0.f; }

        for (int d = 0; d < DD; ++d) {
            float wp = W1[d * HH + h];
            float wq = W1[(DD + d) * HH + h];
            #pragma unroll
            for (int bb_ = 0; bb_ < BS; ++bb_) {
                float ev = sh.e[bb_][d];
                accP[bb_] = fmaf(ev, wp, accP[bb_]);
                accQ[bb_] = fmaf(ev, wq, accQ[bb_]);
            }
        }
        float bv = b1[h];
        #pragma unroll
        for (int bb_ = 0; bb_ < BS; ++bb_) {
            int idx = ((bb_ * N1) + t) * HH + h;
            P[idx]  = accP[bb_];
            Qb[idx] = accQ[bb_] + bv;
            Dd[idx] = accP[bb_] - accQ[bb_];
        }
        __syncthreads();
        if (tid == 0) {
            __threadfence();
            __hip_atomic_fetch_add(&g_proj, 1ull, __ATOMIC_RELEASE,
                                   __HIP_MEMORY_SCOPE_AGENT);
        }
    }

    // ---- barrier 1: all blocks wait for 41 proj arrivals (relaxed polls)
    if (tid == 0) {
        while (__hip_atomic_load(&g_proj, __ATOMIC_RELAXED,
                                 __HIP_MEMORY_SCOPE_AGENT) < (unsigned long long)N1)
            __builtin_amdgcn_s_sleep(32);
        __threadfence();   // acquire: invalidate stale cache before reading P/Qb/Dd
    }
    __syncthreads();

    // ======== phase 2: scores — group covers all 780 pairs of batch b
    {
        const int lg = g * 256 + tid;
        const int p  = lg >> 4;          // pair index, w-descending
        const int t  = lg & 15;

        if (p < NPAIR) {
            int c = (int)((sqrtf(8.f * (float)p + 1.f) - 1.f) * 0.5f);
            while ((c + 1) * (c + 2) / 2 <= p) ++c;
            while (c * (c + 1) / 2 > p) --c;
            const int w    = 40 - c;
            const int i    = p - c * (c + 1) / 2;
            const int k    = i + w;
            const int nj   = w - 1;
            const int n2   = w - 2;
            const int base = n2 * (n2 + 1) * (119 - 2 * n2) / 6;   // == soff(w)

            const float4* Pr  = (const float4*)(P  + ((b * N1 + i) << 8)) + t * 4;
            const float4* Qr  = (const float4*)(Qb + ((b * N1 + k) << 8)) + t * 4;
            const float4* W2r = (const float4*)(W2) + t * 8;

            float4 pp[4], qq[4], wa[4], wb[4];
            #pragma unroll
            for (int q = 0; q < 4; ++q) {
                pp[q] = Pr[q]; qq[q] = Qr[q];
                wa[q] = W2r[q * 2]; wb[q] = W2r[q * 2 + 1];
            }
            const float bb0 = b2[0], bb1 = b2[1];

            const float4* Drow = (const float4*)(Dd + ((b * N1 + i + 1) << 8)) + t * 4;
            float* Sout = S + b * NTRI + base + i * nj;

            for (int jp = 0; jp < nj; ++jp) {
                float s0 = 0.f, s1 = 0.f;
                #pragma unroll
                for (int q = 0; q < 4; ++q) {
                    float4 dd = Drow[q];
                    float r0 = fmaxf(dd.x + qq[q].x - pp[q].x, 0.f);
                    float r1 = fmaxf(dd.y + qq[q].y - pp[q].y, 0.f);
                    float r2 = fmaxf(dd.z + qq[q].z - pp[q].z, 0.f);
                    float r3 = fmaxf(dd.w + qq[q].w - pp[q].w, 0.f);
                    s0 = fmaf(r0, wa[q].x, s0); s1 = fmaf(r0, wa[q].y, s1);
                    s0 = fmaf(r1, wa[q].z, s0); s1 = fmaf(r1, wa[q].w, s1);
                    s0 = fmaf(r2, wb[q].x, s0); s1 = fmaf(r2, wb[q].y, s1);
                    s0 = fmaf(r3, wb[q].z, s0); s1 = fmaf(r3, wb[q].w, s1);
                }
                #pragma unroll
                for (int d = 1; d < 16; d <<= 1) {
                    s0 += __shfl_xor(s0, d);
                    s1 += __shfl_xor(s1, d);
                }
                if (t == 0) {
                    float S0 = s0 + bb0, S1 = s1 + bb1;
                    Sout[jp] = fmaxf(S0, S1) + log1pf(__expf(-fabsf(S0 - S1)));
                }
                Drow += 64;
            }
        }
    }

    // ---- per-b arrival: 49 RMWs per counter, 8 counters in parallel
    __syncthreads();
    if (tid == 0) {
        __threadfence();
        __hip_atomic_fetch_add(&g_sctr[b * 16], 1ull, __ATOMIC_RELEASE,
                               __HIP_MEMORY_SCOPE_AGENT);
    }
    if (g != 0) return;   // only block g==0 of each group runs DP for batch b

    // ---- wait for this batch's 49 score arrivals (single poller per counter)
    if (tid == 0) {
        while (__hip_atomic_load(&g_sctr[b * 16], __ATOMIC_RELAXED,
                                 __HIP_MEMORY_SCOPE_AGENT) < (unsigned long long)GPB)
            __builtin_amdgcn_s_sleep(8);
        __threadfence();
    }
    __syncthreads();

    // ======== phase 3: DP for batch b (verbatim)
    {
        const float4* src = (const float4*)(S + b * NTRI);
        float4* dst = (float4*)sh.dp.Sl;
        for (int x = tid; x < NTRI / 4; x += DPB) dst[x] = src[x];
        if (tid < N_TOK) sh.dp.Btri[tri_base(tid)] = 0.f;
        __syncthreads();

        dp_from<2>(sh.dp.Btri, sh.dp.Sl, tid);

        if (tid == 0) {
            int L = lengths[b];
            out[b] = sh.dp.Btri[BIDX(0, L)];
        }
    }

    // ---- end-of-launch reset (8th DP arrival, epoch via monotonic g_fin)
    if (tid == 0) {
        __threadfence();
        unsigned long long t = __hip_atomic_fetch_add(
            &g_fin, 1ull, __ATOMIC_ACQ_REL, __HIP_MEMORY_SCOPE_AGENT);
        if ((t & 7ull) == 7ull) {
            __hip_atomic_store(&g_proj, 0ull, __ATOMIC_RELAXED,
                               __HIP_MEMORY_SCOPE_AGENT);
            #pragma unroll
            for (int bb_ = 0; bb_ < BS; ++bb_)
                __hip_atomic_store(&g_sctr[bb_ * 16], 0ull, __ATOMIC_RELAXED,
                                   __HIP_MEMORY_SCOPE_AGENT);
        }
    }
}

extern "C" void kernel_launch(void* const* d_in, const int* in_sizes, int n_in,
                              void* d_out, int out_size, void* d_ws, size_t ws_size,
                              hipStream_t stream)
{
    const float* enc = (const float*)d_in[0];
    const float* W1  = (const float*)d_in[1];
    const float* b1  = (const float*)d_in[2];
    const float* W2  = (const float*)d_in[3];
    const float* b2  = (const float*)d_in[4];
    const int* lengths = (const int*)d_in[5];

    float* ws = (float*)d_ws;
    float* P  = ws;
    float* Qb = ws + ROWF;
    float* Dd = ws + 2 * ROWF;
    float* S  = ws + 3 * ROWF;

    k_fused<<<dim3(NBF), dim3(256), 0, stream>>>(
        enc, W1, b1, W2, b2, lengths, P, Qb, Dd, S, (float*)d_out);
}